// Round 1
// baseline (669.002 us; speedup 1.0000x reference)
//
#include <hip/hip_runtime.h>
#include <math.h>

#define N_TOT 524288
#define B_GR  16384
#define CAP   96

// ---------------- small device helpers ----------------
__device__ __forceinline__ float sigf(float x) { return 1.0f / (1.0f + expf(-x)); }

__device__ __forceinline__ float wave_sum(float v) {
#pragma unroll
  for (int o = 32; o > 0; o >>= 1) v += __shfl_xor(v, o);
  return v;
}
__device__ __forceinline__ float wave_max(float v) {
#pragma unroll
  for (int o = 32; o > 0; o >>= 1) v = fmaxf(v, __shfl_xor(v, o));
  return v;
}

// ---------------- 64x64 f32 register-tiled GEMM pieces ----------------
// As/Wt tiles are [64][68] (pad 4 floats keeps 16B alignment, kills bank conflicts)
__device__ __forceinline__ void load_A64(const float* __restrict__ A, size_t lda, int n0, int k0,
                                         float (*As)[68], int tid) {
#pragma unroll
  for (int s = 0; s < 4; s++) {
    int e4 = tid * 4 + s * 1024;
    int r = e4 >> 6, k = e4 & 63;
    *(float4*)&As[r][k] = *(const float4*)&A[(size_t)(n0 + r) * lda + k0 + k];
  }
}
__device__ __forceinline__ void load_Wt64(const float* __restrict__ W, size_t ldw, int c0, int k0,
                                          float (*Wt)[68], int tid) {
#pragma unroll
  for (int s = 0; s < 4; s++) {
    int e4 = tid * 4 + s * 1024;
    int c = e4 >> 6, k = e4 & 63;
    float4 v = *(const float4*)&W[(size_t)(c0 + c) * ldw + k0 + k];
    Wt[k + 0][c] = v.x; Wt[k + 1][c] = v.y; Wt[k + 2][c] = v.z; Wt[k + 3][c] = v.w;
  }
}
__device__ __forceinline__ void mm64(const float (*As)[68], const float (*Wt)[68],
                                     int ty, int tx, float acc[4][4]) {
#pragma unroll
  for (int k4 = 0; k4 < 64; k4 += 4) {
    float4 b0 = *(const float4*)&Wt[k4 + 0][tx * 4];
    float4 b1 = *(const float4*)&Wt[k4 + 1][tx * 4];
    float4 b2 = *(const float4*)&Wt[k4 + 2][tx * 4];
    float4 b3 = *(const float4*)&Wt[k4 + 3][tx * 4];
#pragma unroll
    for (int i = 0; i < 4; i++) {
      float4 a = *(const float4*)&As[ty * 4 + i][k4];
      acc[i][0] = fmaf(a.w, b3.x, fmaf(a.z, b2.x, fmaf(a.y, b1.x, fmaf(a.x, b0.x, acc[i][0]))));
      acc[i][1] = fmaf(a.w, b3.y, fmaf(a.z, b2.y, fmaf(a.y, b1.y, fmaf(a.x, b0.y, acc[i][1]))));
      acc[i][2] = fmaf(a.w, b3.z, fmaf(a.z, b2.z, fmaf(a.y, b1.z, fmaf(a.x, b0.z, acc[i][2]))));
      acc[i][3] = fmaf(a.w, b3.w, fmaf(a.z, b2.w, fmaf(a.y, b1.w, fmaf(a.x, b0.w, acc[i][3]))));
    }
  }
}

// ---------------- K0: graph offsets via binary search (batch_index is sorted) ----------------
__global__ void k_offsets(const int* __restrict__ idx, int* __restrict__ off) {
  int b = blockIdx.x * blockDim.x + threadIdx.x;
  if (b > B_GR) return;
  if (b == B_GR) { off[B_GR] = N_TOT; return; }
  int lo = 0, hi = N_TOT;
  while (lo < hi) { int mid = (lo + hi) >> 1; if (idx[mid] < b) lo = mid + 1; else hi = mid; }
  off[b] = lo;
}

// ---------------- K1: h = X@W1^T + b1, per-block column sum/sumsq partials ----------------
__global__ __launch_bounds__(256) void k_bn_stats(const float* __restrict__ X, const float* __restrict__ W,
                                                  const float* __restrict__ b1,
                                                  float* __restrict__ pSum, float* __restrict__ pSq) {
  __shared__ float As[64][68];
  __shared__ float Wt[64][68];
  int tid = threadIdx.x, ty = tid >> 4, tx = tid & 15;
  int n0 = blockIdx.x * 64;
  float acc[4][4] = {};
  load_A64(X, 64, n0, 0, As, tid);
  load_Wt64(W, 64, 0, 0, Wt, tid);
  __syncthreads();
  mm64(As, Wt, ty, tx, acc);
  float cs[4] = {0, 0, 0, 0}, cq[4] = {0, 0, 0, 0};
#pragma unroll
  for (int j = 0; j < 4; j++) {
    float bb = b1[tx * 4 + j];
#pragma unroll
    for (int i = 0; i < 4; i++) {
      float h = acc[i][j] + bb;
      cs[j] += h; cq[j] += h * h;
    }
  }
  __syncthreads();
  float* red = &As[0][0];  // reuse: 2048 floats needed, 4352 available
#pragma unroll
  for (int j = 0; j < 4; j++) {
    red[ty * 64 + tx * 4 + j] = cs[j];
    red[1024 + ty * 64 + tx * 4 + j] = cq[j];
  }
  __syncthreads();
  if (tid < 64) {
    float s = 0, q = 0;
#pragma unroll
    for (int t = 0; t < 16; t++) { s += red[t * 64 + tid]; q += red[1024 + t * 64 + tid]; }
    pSum[(size_t)blockIdx.x * 64 + tid] = s;
    pSq[(size_t)blockIdx.x * 64 + tid] = q;
  }
}

// ---------------- K2a: finalize BN -> affine aff[0:64]=A, aff[64:128]=C ----------------
__global__ __launch_bounds__(256) void k_bn_final(const float* __restrict__ pSum, const float* __restrict__ pSq,
                                                  const float* __restrict__ bn_g, const float* __restrict__ bn_b,
                                                  const float* __restrict__ c_b1, float* __restrict__ aff) {
  int c = blockIdx.x;
  float s = 0, q = 0;
  for (int i = threadIdx.x; i < 8192; i += 256) {
    s += pSum[(size_t)i * 64 + c];
    q += pSq[(size_t)i * 64 + c];
  }
  __shared__ float rs[256], rq[256];
  rs[threadIdx.x] = s; rq[threadIdx.x] = q;
  __syncthreads();
  for (int st = 128; st > 0; st >>= 1) {
    if (threadIdx.x < st) { rs[threadIdx.x] += rs[threadIdx.x + st]; rq[threadIdx.x] += rq[threadIdx.x + st]; }
    __syncthreads();
  }
  if (threadIdx.x == 0) {
    float mu = rs[0] / (float)N_TOT;
    float var = rq[0] / (float)N_TOT - mu * mu;
    var = fmaxf(var, 0.0f);
    float A = bn_g[c] * rsqrtf(var + 1e-5f);
    aff[c] = A;
    aff[64 + c] = bn_b[c] + (c_b1[c] - mu) * A;
  }
}

// ---------------- K2b: LSTM step1 from biases only; shared part of step-2 gates ----------------
__global__ __launch_bounds__(256) void k_lstm1(const float* __restrict__ bih, const float* __restrict__ bhh,
                                               const float* __restrict__ wih, const float* __restrict__ whh,
                                               float* __restrict__ q1, float* __restrict__ c1, float* __restrict__ sh2) {
  __shared__ float g1[256];
  __shared__ float q1s[64];
  int tid = threadIdx.x;
  g1[tid] = bih[tid] + bhh[tid];
  __syncthreads();
  if (tid < 64) {
    float ig = sigf(g1[tid]);
    float gg = tanhf(g1[128 + tid]);
    float cc = ig * gg;                 // f-gate * c0(=0) drops
    float og = sigf(g1[192 + tid]);
    float qv = og * tanhf(cc);
    q1s[tid] = qv; q1[tid] = qv; c1[tid] = cc;
  }
  __syncthreads();
  float acc = g1[tid];
  for (int k = 0; k < 64; k++)
    acc = fmaf(wih[(size_t)tid * 128 + k] + whh[(size_t)tid * 64 + k], q1s[k], acc);
  sh2[tid] = acc;
}

// ---------------- K3: recompute h, BN-affine+ReLU, p, lambda; preserve count ----------------
__global__ __launch_bounds__(256) void k_gate(const float* __restrict__ X, const float* __restrict__ W,
                                              const float* __restrict__ aff, const float* __restrict__ w2,
                                              const float* __restrict__ cb2, const float* __restrict__ eps_gate,
                                              float* __restrict__ lamWS, float* __restrict__ lamOut,
                                              int* __restrict__ presCnt) {
  __shared__ float As[64][68];
  __shared__ float Wt[64][68];
  __shared__ float predR[64][17];
  __shared__ float A2s[64], C2s[64], w2s[64];
  int tid = threadIdx.x, ty = tid >> 4, tx = tid & 15;
  int n0 = blockIdx.x * 64;
  if (tid < 64) { A2s[tid] = aff[tid]; C2s[tid] = aff[64 + tid]; w2s[tid] = w2[tid]; }
  float acc[4][4] = {};
  load_A64(X, 64, n0, 0, As, tid);
  load_Wt64(W, 64, 0, 0, Wt, tid);
  __syncthreads();
  mm64(As, Wt, ty, tx, acc);
  float pp[4] = {0, 0, 0, 0};
#pragma unroll
  for (int j = 0; j < 4; j++) {
    int c = tx * 4 + j;
    float A2 = A2s[c], C2 = C2s[c], wv = w2s[c];
#pragma unroll
    for (int i = 0; i < 4; i++) {
      float v = fmaxf(fmaf(acc[i][j], A2, C2), 0.0f);
      pp[i] = fmaf(v, wv, pp[i]);
    }
  }
#pragma unroll
  for (int i = 0; i < 4; i++) predR[ty * 4 + i][tx] = pp[i];
  __syncthreads();
  if (tid < 64) {
    float p = cb2[0];
#pragma unroll
    for (int t = 0; t < 16; t++) p += predR[tid][t];
    float eg = eps_gate[n0 + tid];
    float eps = 0.9999f - 0.9998f * eg;      // (bias-(1-bias))*eg + (1-bias), bias=1e-4
    float gi = logf(eps) - logf(1.0f - eps);
    float lam = sigf(gi + p);
    lamWS[n0 + tid] = lam;
    lamOut[n0 + tid] = lam;
    unsigned long long m = __ballot(p > 0.0f);
    if (tid == 0) atomicAdd(presCnt, (int)__popcll(m));
  }
}

// ---------------- K4: per-graph stats, noisy, KL, fused attention step 1 ----------------
__global__ __launch_bounds__(256) void k_graph(const float* __restrict__ X, const float* __restrict__ noise,
                                               const float* __restrict__ lam, const int* __restrict__ off,
                                               const float* __restrict__ q1g,
                                               float* __restrict__ noisy, float* __restrict__ r1,
                                               float* __restrict__ klp, float* __restrict__ esG) {
  __shared__ float Xs[CAP][64];
  __shared__ float Ns[CAP][64];
  __shared__ float lams[CAP];
  __shared__ float es[CAP];
  __shared__ float meanS[64], stdS[64], invS[64], q1s[64];
  __shared__ float red[4][64];
  __shared__ float red2[4][64];
  __shared__ float scal[4];  // 0: denom, 1: sum(1-lam)^2, 2: S1
  int b = blockIdx.x;
  int n0 = off[b], cnt = off[b + 1] - n0;
  int tid = threadIdx.x, w = tid >> 6, lane = tid & 63;
  if (cnt == 0) {
    if (tid < 64) r1[(size_t)b * 64 + tid] = 0.0f;
    if (tid == 0) klp[b] = 0.0f;
    return;
  }
  int stg = min(cnt, CAP);
  for (int e4 = tid * 4; e4 < stg * 64; e4 += 1024) {
    int n = e4 >> 6, d = e4 & 63;
    *(float4*)&Xs[n][d] = *(const float4*)&X[(size_t)(n0 + n) * 64 + d];
  }
  if (tid < stg) lams[tid] = lam[n0 + tid];
  if (tid < 64) q1s[tid] = q1g[tid];
  __syncthreads();
  // stats
  {
    float s = 0, q = 0;
    for (int n = w; n < cnt; n += 4) {
      float xv = (n < CAP) ? Xs[n][lane] : X[(size_t)(n0 + n) * 64 + lane];
      s += xv; q = fmaf(xv, xv, q);
    }
    red[w][lane] = s; red2[w][lane] = q;
  }
  __syncthreads();
  if (tid < 64) {
    float s = red[0][tid] + red[1][tid] + red[2][tid] + red[3][tid];
    float q = red2[0][tid] + red2[1][tid] + red2[2][tid] + red2[3][tid];
    float c = (float)cnt;
    float mean = s / c;
    float var = (q - c * mean * mean) / fmaxf(c - 1.0f, 1.0f);
    var = fmaxf(var, 0.0f);
    float sd = sqrtf(var);
    float inv = 1.0f / (sd + 1e-7f);
    meanS[tid] = mean; stdS[tid] = sd; invS[tid] = inv;
    float t = wave_sum(sd * sd * inv * inv);
    if (tid == 0) scal[2] = t;
  }
  __syncthreads();
  // noisy + e (attention-1 logits) + t2 partials
  float t2acc = 0.0f;
  for (int n = w; n < cnt; n += 4) {
    float lamn = (n < CAP) ? lams[n] : lam[n0 + n];
    float om = 1.0f - lamn;
    float xv = (n < CAP) ? Xs[n][lane] : X[(size_t)(n0 + n) * 64 + lane];
    float nz = noise[(size_t)(n0 + n) * 64 + lane];
    float mean = meanS[lane], sd = stdS[lane], inv = invS[lane];
    float nv = lamn * xv + om * mean + nz * om * sd;
    noisy[(size_t)(n0 + n) * 64 + lane] = nv;
    if (n < CAP) Ns[n][lane] = nv;
    float diff = xv - mean;
    t2acc = fmaf(lamn * lamn * diff * diff, inv * inv, t2acc);
    float ev = wave_sum(nv * q1s[lane]);
    if (lane == 0) { if (n < CAP) es[n] = ev; else esG[n0 + n] = ev; }
  }
  red[w][lane] = t2acc;
  if (cnt > CAP) __threadfence();
  __syncthreads();
  // softmax (wave 0)
  if (w == 0) {
    float mx = -INFINITY;
    for (int n = lane; n < cnt; n += 64) mx = fmaxf(mx, (n < CAP) ? es[n] : esG[n0 + n]);
    mx = wave_max(mx);
    float ds = 0.0f, so = 0.0f;
    for (int n = lane; n < cnt; n += 64) {
      float e = (n < CAP) ? es[n] : esG[n0 + n];
      float wv = expf(e - mx);
      if (n < CAP) es[n] = wv; else esG[n0 + n] = wv;
      ds += wv;
      float l = (n < CAP) ? lams[n] : lam[n0 + n];
      so += (1.0f - l) * (1.0f - l);
    }
    ds = wave_sum(ds); so = wave_sum(so);
    if (lane == 0) { scal[0] = ds; scal[1] = so; }
  }
  if (cnt > CAP) __threadfence();
  __syncthreads();
  // r1 = sum_n w_n * noisy_n / denom
  {
    float acc = 0.0f;
    for (int n = w; n < cnt; n += 4) {
      float wv = (n < CAP) ? es[n] : esG[n0 + n];
      float nv = (n < CAP) ? Ns[n][lane] : noisy[(size_t)(n0 + n) * 64 + lane];
      acc = fmaf(wv, nv, acc);
    }
    red2[w][lane] = acc;
  }
  __syncthreads();
  if (tid < 64) {
    float rv = (red2[0][tid] + red2[1][tid] + red2[2][tid] + red2[3][tid]) / scal[0];
    r1[(size_t)b * 64 + tid] = rv;
    float t2d = red[0][tid] + red[1][tid] + red[2][tid] + red[3][tid];
    float t2tot = wave_sum(t2d);
    if (tid == 0) klp[b] = 0.5f * scal[1] * scal[2] + t2tot;  // D*t1_b + sum_d t2_bd
  }
}

// ---------------- K5: Set2Set step-2 LSTM: gates = sh2 + r1 @ R^T, 16 graphs/block ----------------
__global__ __launch_bounds__(256) void k_lstm2(const float* __restrict__ r1, const float* __restrict__ wih,
                                               const float* __restrict__ sh2, const float* __restrict__ c1g,
                                               float* __restrict__ qstar) {
  __shared__ float Rs[2][64][64];   // [gate pair][k][d]
  __shared__ float r1s[16][64];
  __shared__ float sh2s[256], c1s[64];
  int tid = threadIdx.x;
  int d = tid & 63, rg = tid >> 6;
  int g0 = blockIdx.x * 16;
  sh2s[tid] = sh2[tid];
  if (tid < 64) c1s[tid] = c1g[tid];
  {
    int e4 = tid * 4;
    int r = e4 >> 6, k = e4 & 63;
    *(float4*)&r1s[r][k] = *(const float4*)&r1[(size_t)(g0 + r) * 64 + k];
  }
  float acc[4][4] = {};  // [row i][gate j]
#pragma unroll
  for (int jp = 0; jp < 2; jp++) {
    __syncthreads();
    {
      int j2 = tid >> 6, dd = tid & 63;   // j2 in 0..3 -> two loads each half
      int jj = (jp * 2) + (j2 & 1);
      // each thread pair-loads: threads 0..127 load gate jp*2, 128..255 load gate jp*2+1
      int gate = jp * 2 + (tid >= 128 ? 1 : 0);
      int dd2 = tid & 63;
      int half = (tid >> 6) & 1;          // two row-halves per gate? no: 64 rows per gate, 128 threads
      // simpler: 128 threads per gate, each handles rows dd2 with half*0 offset (only 64 rows) -> use 64 threads/gate twice
      (void)jj; (void)j2; (void)dd; (void)half;
      if ((tid & 127) < 64) {
        int row = gate * 64 + dd2;        // Wih row index (within 256)
        const float* src = &wih[(size_t)row * 128 + 64];
        for (int k = 0; k < 64; k += 4) {
          float4 v = *(const float4*)&src[k];
          Rs[gate - jp * 2][k + 0][dd2] = v.x;
          Rs[gate - jp * 2][k + 1][dd2] = v.y;
          Rs[gate - jp * 2][k + 2][dd2] = v.z;
          Rs[gate - jp * 2][k + 3][dd2] = v.w;
        }
      }
    }
    __syncthreads();
    for (int k = 0; k < 64; k++) {
      float bj0 = Rs[0][k][d];
      float bj1 = Rs[1][k][d];
#pragma unroll
      for (int i = 0; i < 4; i++) {
        float a = r1s[rg * 4 + i][k];
        acc[i][jp * 2 + 0] = fmaf(a, bj0, acc[i][jp * 2 + 0]);
        acc[i][jp * 2 + 1] = fmaf(a, bj1, acc[i][jp * 2 + 1]);
      }
    }
  }
#pragma unroll
  for (int i = 0; i < 4; i++) {
    int row = g0 + rg * 4 + i;
    float ig = acc[i][0] + sh2s[d];
    float fg = acc[i][1] + sh2s[64 + d];
    float gg = acc[i][2] + sh2s[128 + d];
    float og = acc[i][3] + sh2s[192 + d];
    float c2 = sigf(fg) * c1s[d] + sigf(ig) * tanhf(gg);
    float q2 = sigf(og) * tanhf(c2);
    qstar[(size_t)row * 128 + d] = q2;
  }
}

// ---------------- K6: attention step 2, writes qstar second half ----------------
__global__ __launch_bounds__(256) void k_attn2(const float* __restrict__ noisy, const int* __restrict__ off,
                                               float* __restrict__ qstar, float* __restrict__ esG) {
  __shared__ float Ns[CAP][64];
  __shared__ float es[CAP];
  __shared__ float q2s[64];
  __shared__ float red[4][64];
  __shared__ float scal[1];
  int b = blockIdx.x;
  int n0 = off[b], cnt = off[b + 1] - n0;
  int tid = threadIdx.x, w = tid >> 6, lane = tid & 63;
  if (tid < 64) q2s[tid] = qstar[(size_t)b * 128 + tid];
  if (cnt == 0) {
    if (tid < 64) qstar[(size_t)b * 128 + 64 + tid] = 0.0f;
    return;
  }
  int stg = min(cnt, CAP);
  for (int e4 = tid * 4; e4 < stg * 64; e4 += 1024) {
    int n = e4 >> 6, d = e4 & 63;
    *(float4*)&Ns[n][d] = *(const float4*)&noisy[(size_t)(n0 + n) * 64 + d];
  }
  __syncthreads();
  for (int n = w; n < cnt; n += 4) {
    float nv = (n < CAP) ? Ns[n][lane] : noisy[(size_t)(n0 + n) * 64 + lane];
    float ev = wave_sum(nv * q2s[lane]);
    if (lane == 0) { if (n < CAP) es[n] = ev; else esG[n0 + n] = ev; }
  }
  if (cnt > CAP) __threadfence();
  __syncthreads();
  if (w == 0) {
    float mx = -INFINITY;
    for (int n = lane; n < cnt; n += 64) mx = fmaxf(mx, (n < CAP) ? es[n] : esG[n0 + n]);
    mx = wave_max(mx);
    float ds = 0.0f;
    for (int n = lane; n < cnt; n += 64) {
      float e = (n < CAP) ? es[n] : esG[n0 + n];
      float wv = expf(e - mx);
      if (n < CAP) es[n] = wv; else esG[n0 + n] = wv;
      ds += wv;
    }
    ds = wave_sum(ds);
    if (lane == 0) scal[0] = ds;
  }
  if (cnt > CAP) __threadfence();
  __syncthreads();
  {
    float acc = 0.0f;
    for (int n = w; n < cnt; n += 4) {
      float wv = (n < CAP) ? es[n] : esG[n0 + n];
      float nv = (n < CAP) ? Ns[n][lane] : noisy[(size_t)(n0 + n) * 64 + lane];
      acc = fmaf(wv, nv, acc);
    }
    red[w][lane] = acc;
  }
  __syncthreads();
  if (tid < 64) {
    float rv = (red[0][tid] + red[1][tid] + red[2][tid] + red[3][tid]) / scal[0];
    qstar[(size_t)b * 128 + 64 + tid] = rv;
  }
}

// ---------------- K7/8/9: predictor linear layers ----------------
template <int KDIM, bool RELU>
__global__ __launch_bounds__(256) void k_linear(const float* __restrict__ A, const float* __restrict__ W,
                                                const float* __restrict__ bias, float* __restrict__ C, int ldc) {
  __shared__ float As[64][68];
  __shared__ float Wt[64][68];
  int tid = threadIdx.x, ty = tid >> 4, tx = tid & 15;
  int n0 = blockIdx.x * 64, c0 = blockIdx.y * 64;
  float acc[4][4] = {};
  for (int kt = 0; kt < KDIM; kt += 64) {
    __syncthreads();
    load_A64(A, KDIM, n0, kt, As, tid);
    load_Wt64(W, KDIM, c0, kt, Wt, tid);
    __syncthreads();
    mm64(As, Wt, ty, tx, acc);
  }
#pragma unroll
  for (int i = 0; i < 4; i++) {
    int row = n0 + ty * 4 + i;
    float4 o;
    float v0 = acc[i][0] + bias[c0 + tx * 4 + 0];
    float v1 = acc[i][1] + bias[c0 + tx * 4 + 1];
    float v2 = acc[i][2] + bias[c0 + tx * 4 + 2];
    float v3 = acc[i][3] + bias[c0 + tx * 4 + 3];
    if (RELU) { v0 = fmaxf(v0, 0.f); v1 = fmaxf(v1, 0.f); v2 = fmaxf(v2, 0.f); v3 = fmaxf(v3, 0.f); }
    o.x = v0; o.y = v1; o.z = v2; o.w = v3;
    *(float4*)&C[(size_t)row * ldc + c0 + tx * 4] = o;
  }
}

// ---------------- K10: final scalars ----------------
__global__ __launch_bounds__(256) void k_final(const float* __restrict__ klp, const int* __restrict__ presCnt,
                                               float* __restrict__ out) {
  __shared__ float red[256];
  float s = 0.0f;
  for (int i = threadIdx.x; i < B_GR; i += 256) s += klp[i];
  red[threadIdx.x] = s;
  __syncthreads();
  for (int st = 128; st > 0; st >>= 1) {
    if (threadIdx.x < st) red[threadIdx.x] += red[threadIdx.x + st];
    __syncthreads();
  }
  if (threadIdx.x == 0) {
    out[(size_t)B_GR * 64] = red[0] / (float)(B_GR * 64);
    out[(size_t)B_GR * 64 + 1] = (float)(*presCnt) / (float)N_TOT;
  }
}

// ---------------- launcher ----------------
extern "C" void kernel_launch(void* const* d_in, const int* in_sizes, int n_in,
                              void* d_out, int out_size, void* d_ws, size_t ws_size,
                              hipStream_t stream) {
  const float* features = (const float*)d_in[0];
  const int*   bidx     = (const int*)d_in[1];
  const float* eps_gate = (const float*)d_in[2];
  const float* noise    = (const float*)d_in[3];
  const float* c_w1 = (const float*)d_in[4];
  const float* c_b1 = (const float*)d_in[5];
  const float* bn_g = (const float*)d_in[6];
  const float* bn_b = (const float*)d_in[7];
  const float* c_w2 = (const float*)d_in[8];
  const float* c_b2 = (const float*)d_in[9];
  const float* wih  = (const float*)d_in[10];
  const float* whh  = (const float*)d_in[11];
  const float* bih  = (const float*)d_in[12];
  const float* bhh  = (const float*)d_in[13];
  const float* p_w1 = (const float*)d_in[14];
  const float* p_b1 = (const float*)d_in[15];
  const float* p_w2 = (const float*)d_in[16];
  const float* p_b2 = (const float*)d_in[17];
  const float* p_w3 = (const float*)d_in[18];
  const float* p_b3 = (const float*)d_in[19];
  float* out = (float*)d_out;

  float* wsf   = (float*)d_ws;
  int*   offp  = (int*)wsf;                                 // (B+1) ints
  float* pSum  = wsf + 16448;
  float* pSq   = pSum + 524288;
  float* aff   = pSq + 524288;                              // 128
  float* q1w   = aff + 128;
  float* c1w   = q1w + 64;
  float* sh2w  = c1w + 64;                                  // 256
  float* lamw  = sh2w + 256;                                // N
  float* noisyw = lamw + (size_t)N_TOT;                     // N*64
  float* r1w    = noisyw + (size_t)N_TOT * 64;              // B*64
  float* qstarw = r1w + (size_t)B_GR * 64;                  // B*128
  float* z1w    = qstarw + (size_t)B_GR * 128;              // B*256
  float* z2w    = z1w + (size_t)B_GR * 256;                 // B*128
  float* klpw   = z2w + (size_t)B_GR * 128;                 // B
  int*   presw  = (int*)(klpw + B_GR);
  float* esGw   = (float*)(presw + 64);                     // N (overflow only)

  float* lamOut = out + (size_t)B_GR * 64 + 2;

  hipMemsetAsync(presw, 0, sizeof(int), stream);

  k_offsets<<<(B_GR + 1 + 255) / 256, 256, 0, stream>>>(bidx, offp);
  k_bn_stats<<<N_TOT / 64, 256, 0, stream>>>(features, c_w1, c_b1, pSum, pSq);
  k_bn_final<<<64, 256, 0, stream>>>(pSum, pSq, bn_g, bn_b, c_b1, aff);
  k_lstm1<<<1, 256, 0, stream>>>(bih, bhh, wih, whh, q1w, c1w, sh2w);
  k_gate<<<N_TOT / 64, 256, 0, stream>>>(features, c_w1, aff, c_w2, c_b2, eps_gate, lamw, lamOut, presw);
  k_graph<<<B_GR, 256, 0, stream>>>(features, noise, lamw, offp, q1w, noisyw, r1w, klpw, esGw);
  k_lstm2<<<B_GR / 16, 256, 0, stream>>>(r1w, wih, sh2w, c1w, qstarw);
  k_attn2<<<B_GR, 256, 0, stream>>>(noisyw, offp, qstarw, esGw);
  k_linear<128, true><<<dim3(B_GR / 64, 4), 256, 0, stream>>>(qstarw, p_w1, p_b1, z1w, 256);
  k_linear<256, true><<<dim3(B_GR / 64, 2), 256, 0, stream>>>(z1w, p_w2, p_b2, z2w, 128);
  k_linear<128, false><<<dim3(B_GR / 64, 1), 256, 0, stream>>>(z2w, p_w3, p_b3, out, 64);
  k_final<<<1, 256, 0, stream>>>(klpw, presw, out);
}

// Round 2
// 525.345 us; speedup vs baseline: 1.2735x; 1.2735x over previous
//
#include <hip/hip_runtime.h>
#include <math.h>

#define N_TOT 524288
#define B_GR  16384

// ---------------- small device helpers ----------------
__device__ __forceinline__ float sigf(float x) { return 1.0f / (1.0f + expf(-x)); }

__device__ __forceinline__ float wave_sum(float v) {
#pragma unroll
  for (int o = 32; o > 0; o >>= 1) v += __shfl_xor(v, o);
  return v;
}

// ---------------- 64x64 f32 register-tiled GEMM pieces ----------------
// As/Wt tiles are [64][68] (pad 4 floats keeps 16B alignment, kills bank conflicts)
__device__ __forceinline__ void load_A64(const float* __restrict__ A, size_t lda, int n0, int k0,
                                         float (*As)[68], int tid) {
#pragma unroll
  for (int s = 0; s < 4; s++) {
    int e4 = tid * 4 + s * 1024;
    int r = e4 >> 6, k = e4 & 63;
    *(float4*)&As[r][k] = *(const float4*)&A[(size_t)(n0 + r) * lda + k0 + k];
  }
}
__device__ __forceinline__ void load_Wt64(const float* __restrict__ W, size_t ldw, int c0, int k0,
                                          float (*Wt)[68], int tid) {
#pragma unroll
  for (int s = 0; s < 4; s++) {
    int e4 = tid * 4 + s * 1024;
    int c = e4 >> 6, k = e4 & 63;
    float4 v = *(const float4*)&W[(size_t)(c0 + c) * ldw + k0 + k];
    Wt[k + 0][c] = v.x; Wt[k + 1][c] = v.y; Wt[k + 2][c] = v.z; Wt[k + 3][c] = v.w;
  }
}
__device__ __forceinline__ void mm64(const float (*As)[68], const float (*Wt)[68],
                                     int ty, int tx, float acc[4][4]) {
#pragma unroll
  for (int k4 = 0; k4 < 64; k4 += 4) {
    float4 b0 = *(const float4*)&Wt[k4 + 0][tx * 4];
    float4 b1 = *(const float4*)&Wt[k4 + 1][tx * 4];
    float4 b2 = *(const float4*)&Wt[k4 + 2][tx * 4];
    float4 b3 = *(const float4*)&Wt[k4 + 3][tx * 4];
#pragma unroll
    for (int i = 0; i < 4; i++) {
      float4 a = *(const float4*)&As[ty * 4 + i][k4];
      acc[i][0] = fmaf(a.w, b3.x, fmaf(a.z, b2.x, fmaf(a.y, b1.x, fmaf(a.x, b0.x, acc[i][0]))));
      acc[i][1] = fmaf(a.w, b3.y, fmaf(a.z, b2.y, fmaf(a.y, b1.y, fmaf(a.x, b0.y, acc[i][1]))));
      acc[i][2] = fmaf(a.w, b3.z, fmaf(a.z, b2.z, fmaf(a.y, b1.z, fmaf(a.x, b0.z, acc[i][2]))));
      acc[i][3] = fmaf(a.w, b3.w, fmaf(a.z, b2.w, fmaf(a.y, b1.w, fmaf(a.x, b0.w, acc[i][3]))));
    }
  }
}

// ---------------- K0: graph offsets via binary search (batch_index is sorted) ----------------
__global__ void k_offsets(const int* __restrict__ idx, int* __restrict__ off) {
  int b = blockIdx.x * blockDim.x + threadIdx.x;
  if (b > B_GR) return;
  if (b == B_GR) { off[B_GR] = N_TOT; return; }
  int lo = 0, hi = N_TOT;
  while (lo < hi) { int mid = (lo + hi) >> 1; if (idx[mid] < b) lo = mid + 1; else hi = mid; }
  off[b] = lo;
}

// ---------------- K1: h = X@W1^T + b1, per-block column sum/sumsq partials ----------------
__global__ __launch_bounds__(256) void k_bn_stats(const float* __restrict__ X, const float* __restrict__ W,
                                                  const float* __restrict__ b1,
                                                  float* __restrict__ pSum, float* __restrict__ pSq) {
  __shared__ float As[64][68];
  __shared__ float Wt[64][68];
  int tid = threadIdx.x, ty = tid >> 4, tx = tid & 15;
  int n0 = blockIdx.x * 64;
  float acc[4][4] = {};
  load_A64(X, 64, n0, 0, As, tid);
  load_Wt64(W, 64, 0, 0, Wt, tid);
  __syncthreads();
  mm64(As, Wt, ty, tx, acc);
  float cs[4] = {0, 0, 0, 0}, cq[4] = {0, 0, 0, 0};
#pragma unroll
  for (int j = 0; j < 4; j++) {
    float bb = b1[tx * 4 + j];
#pragma unroll
    for (int i = 0; i < 4; i++) {
      float h = acc[i][j] + bb;
      cs[j] += h; cq[j] += h * h;
    }
  }
  __syncthreads();
  float* red = &As[0][0];  // reuse: 2048 floats needed, 4352 available
#pragma unroll
  for (int j = 0; j < 4; j++) {
    red[ty * 64 + tx * 4 + j] = cs[j];
    red[1024 + ty * 64 + tx * 4 + j] = cq[j];
  }
  __syncthreads();
  if (tid < 64) {
    float s = 0, q = 0;
#pragma unroll
    for (int t = 0; t < 16; t++) { s += red[t * 64 + tid]; q += red[1024 + t * 64 + tid]; }
    pSum[(size_t)blockIdx.x * 64 + tid] = s;
    pSq[(size_t)blockIdx.x * 64 + tid] = q;
  }
}

// ---------------- K2a: finalize BN -> affine aff[0:64]=A, aff[64:128]=C ----------------
__global__ __launch_bounds__(256) void k_bn_final(const float* __restrict__ pSum, const float* __restrict__ pSq,
                                                  const float* __restrict__ bn_g, const float* __restrict__ bn_b,
                                                  const float* __restrict__ c_b1, float* __restrict__ aff) {
  int c = blockIdx.x;
  float s = 0, q = 0;
  for (int i = threadIdx.x; i < 8192; i += 256) {
    s += pSum[(size_t)i * 64 + c];
    q += pSq[(size_t)i * 64 + c];
  }
  __shared__ float rs[256], rq[256];
  rs[threadIdx.x] = s; rq[threadIdx.x] = q;
  __syncthreads();
  for (int st = 128; st > 0; st >>= 1) {
    if (threadIdx.x < st) { rs[threadIdx.x] += rs[threadIdx.x + st]; rq[threadIdx.x] += rq[threadIdx.x + st]; }
    __syncthreads();
  }
  if (threadIdx.x == 0) {
    float mu = rs[0] / (float)N_TOT;
    float var = rq[0] / (float)N_TOT - mu * mu;
    var = fmaxf(var, 0.0f);
    float A = bn_g[c] * rsqrtf(var + 1e-5f);
    aff[c] = A;
    aff[64 + c] = bn_b[c] + (c_b1[c] - mu) * A;
  }
}

// ---------------- K2b: LSTM step1 from biases only; shared part of step-2 gates ----------------
__global__ __launch_bounds__(256) void k_lstm1(const float* __restrict__ bih, const float* __restrict__ bhh,
                                               const float* __restrict__ wih, const float* __restrict__ whh,
                                               float* __restrict__ q1, float* __restrict__ c1, float* __restrict__ sh2) {
  __shared__ float g1[256];
  __shared__ float q1s[64];
  int tid = threadIdx.x;
  g1[tid] = bih[tid] + bhh[tid];
  __syncthreads();
  if (tid < 64) {
    float ig = sigf(g1[tid]);
    float gg = tanhf(g1[128 + tid]);
    float cc = ig * gg;                 // f-gate * c0(=0) drops
    float og = sigf(g1[192 + tid]);
    float qv = og * tanhf(cc);
    q1s[tid] = qv; q1[tid] = qv; c1[tid] = cc;
  }
  __syncthreads();
  float acc = g1[tid];
  for (int k = 0; k < 64; k++)
    acc = fmaf(wih[(size_t)tid * 128 + k] + whh[(size_t)tid * 64 + k], q1s[k], acc);
  sh2[tid] = acc;
}

// ---------------- K3: recompute h, BN-affine+ReLU, p, lambda; preserve count ----------------
__global__ __launch_bounds__(256) void k_gate(const float* __restrict__ X, const float* __restrict__ W,
                                              const float* __restrict__ aff, const float* __restrict__ w2,
                                              const float* __restrict__ cb2, const float* __restrict__ eps_gate,
                                              float* __restrict__ lamWS, float* __restrict__ lamOut,
                                              int* __restrict__ presCnt) {
  __shared__ float As[64][68];
  __shared__ float Wt[64][68];
  __shared__ float predR[64][17];
  __shared__ float A2s[64], C2s[64], w2s[64];
  int tid = threadIdx.x, ty = tid >> 4, tx = tid & 15;
  int n0 = blockIdx.x * 64;
  if (tid < 64) { A2s[tid] = aff[tid]; C2s[tid] = aff[64 + tid]; w2s[tid] = w2[tid]; }
  float acc[4][4] = {};
  load_A64(X, 64, n0, 0, As, tid);
  load_Wt64(W, 64, 0, 0, Wt, tid);
  __syncthreads();
  mm64(As, Wt, ty, tx, acc);
  float pp[4] = {0, 0, 0, 0};
#pragma unroll
  for (int j = 0; j < 4; j++) {
    int c = tx * 4 + j;
    float A2 = A2s[c], C2 = C2s[c], wv = w2s[c];
#pragma unroll
    for (int i = 0; i < 4; i++) {
      float v = fmaxf(fmaf(acc[i][j], A2, C2), 0.0f);
      pp[i] = fmaf(v, wv, pp[i]);
    }
  }
#pragma unroll
  for (int i = 0; i < 4; i++) predR[ty * 4 + i][tx] = pp[i];
  __syncthreads();
  if (tid < 64) {
    float p = cb2[0];
#pragma unroll
    for (int t = 0; t < 16; t++) p += predR[tid][t];
    float eg = eps_gate[n0 + tid];
    float eps = 0.9999f - 0.9998f * eg;      // (bias-(1-bias))*eg + (1-bias), bias=1e-4
    float gi = logf(eps) - logf(1.0f - eps);
    float lam = sigf(gi + p);
    lamWS[n0 + tid] = lam;
    lamOut[n0 + tid] = lam;
    unsigned long long m = __ballot(p > 0.0f);
    if (tid == 0) atomicAdd(presCnt, (int)__popcll(m));
  }
}

// ---------------- K4: wave-per-graph: stats, noisy, KL, online-softmax attention step 1 ----------------
// One 64-lane wave owns one graph; lane = feature dim d. All stats/KL accumulators are
// lane-local; only the e = noisy.q1 dot needs cross-lane (6 shuffles). Online (flash-style)
// softmax folds logits/max/denom/weighted-sum into ONE pass -> no LDS, no barriers,
// no noisy re-read.
__global__ __launch_bounds__(256) void k_graph(const float* __restrict__ X, const float* __restrict__ noise,
                                               const float* __restrict__ lam, const int* __restrict__ off,
                                               const float* __restrict__ q1g,
                                               float* __restrict__ noisy, float* __restrict__ r1,
                                               float* __restrict__ klp) {
  int wg = blockIdx.x * 4 + (threadIdx.x >> 6);
  int lane = threadIdx.x & 63;
  int n0 = off[wg], cnt = off[wg + 1] - n0;
  if (cnt == 0) {
    r1[(size_t)wg * 64 + lane] = 0.0f;
    if (lane == 0) klp[wg] = 0.0f;
    return;
  }
  float q1v = q1g[lane];
  const float* xp = X + (size_t)n0 * 64 + lane;
  // pass 1: per-dim mean / unbiased std (lane-local)
  float s = 0.f, q = 0.f;
  for (int n = 0; n < cnt; n++) {
    float xv = xp[(size_t)n * 64];
    s += xv; q = fmaf(xv, xv, q);
  }
  float c = (float)cnt;
  float mean = s / c;
  float var = fmaxf((q - c * mean * mean) / fmaxf(c - 1.f, 1.f), 0.f);
  float sd = sqrtf(var);
  float inv = 1.f / (sd + 1e-7f);
  float S1 = wave_sum(sd * sd * inv * inv);   // sum_d sd^2/(sd+eps)^2
  // pass 2: noisy + KL partials + online-softmax attention step 1
  const float* zp = noise + (size_t)n0 * 64 + lane;
  float* nw = noisy + (size_t)n0 * 64 + lane;
  float t2acc = 0.f, sumOm2 = 0.f;
  float mrun = -INFINITY, lrun = 0.f, racc = 0.f;
  for (int n = 0; n < cnt; n++) {
    float lamn = lam[n0 + n];                  // scalar broadcast
    float om = 1.f - lamn;
    float xv = xp[(size_t)n * 64];
    float nz = zp[(size_t)n * 64];
    float nv = fmaf(lamn, xv, om * mean) + nz * (om * sd);
    nw[(size_t)n * 64] = nv;
    float ld = lamn * (xv - mean) * inv;
    t2acc = fmaf(ld, ld, t2acc);
    sumOm2 = fmaf(om, om, sumOm2);             // identical across lanes (scalar)
    float ev = wave_sum(nv * q1v);             // all lanes get e_n
    float mnew = fmaxf(mrun, ev);
    float scale = expf(mrun - mnew);           // first iter: exp(-inf)=0
    float p = expf(ev - mnew);
    lrun = fmaf(lrun, scale, p);
    racc = fmaf(racc, scale, p * nv);
    mrun = mnew;
  }
  r1[(size_t)wg * 64 + lane] = racc / lrun;
  float t2tot = wave_sum(t2acc);
  if (lane == 0) klp[wg] = fmaf(0.5f * sumOm2, S1, t2tot);
}

// ---------------- K5: Set2Set step-2 LSTM: gates = sh2 + r1 @ R^T, 16 graphs/block ----------------
__global__ __launch_bounds__(256) void k_lstm2(const float* __restrict__ r1, const float* __restrict__ wih,
                                               const float* __restrict__ sh2, const float* __restrict__ c1g,
                                               float* __restrict__ qstar) {
  __shared__ float Rs[2][64][64];   // [gate pair][k][d]
  __shared__ float r1s[16][64];
  __shared__ float sh2s[256], c1s[64];
  int tid = threadIdx.x;
  int d = tid & 63, rg = tid >> 6;
  int g0 = blockIdx.x * 16;
  sh2s[tid] = sh2[tid];
  if (tid < 64) c1s[tid] = c1g[tid];
  {
    int e4 = tid * 4;
    int r = e4 >> 6, k = e4 & 63;
    *(float4*)&r1s[r][k] = *(const float4*)&r1[(size_t)(g0 + r) * 64 + k];
  }
  float acc[4][4] = {};  // [row i][gate j]
#pragma unroll
  for (int jp = 0; jp < 2; jp++) {
    __syncthreads();
    {
      int gate = jp * 2 + (tid >= 128 ? 1 : 0);
      int dd2 = tid & 63;
      if ((tid & 127) < 64) {
        int row = gate * 64 + dd2;        // Wih row index (within 256)
        const float* src = &wih[(size_t)row * 128 + 64];
        for (int k = 0; k < 64; k += 4) {
          float4 v = *(const float4*)&src[k];
          Rs[gate - jp * 2][k + 0][dd2] = v.x;
          Rs[gate - jp * 2][k + 1][dd2] = v.y;
          Rs[gate - jp * 2][k + 2][dd2] = v.z;
          Rs[gate - jp * 2][k + 3][dd2] = v.w;
        }
      }
    }
    __syncthreads();
    for (int k = 0; k < 64; k++) {
      float bj0 = Rs[0][k][d];
      float bj1 = Rs[1][k][d];
#pragma unroll
      for (int i = 0; i < 4; i++) {
        float a = r1s[rg * 4 + i][k];
        acc[i][jp * 2 + 0] = fmaf(a, bj0, acc[i][jp * 2 + 0]);
        acc[i][jp * 2 + 1] = fmaf(a, bj1, acc[i][jp * 2 + 1]);
      }
    }
  }
#pragma unroll
  for (int i = 0; i < 4; i++) {
    int row = g0 + rg * 4 + i;
    float ig = acc[i][0] + sh2s[d];
    float fg = acc[i][1] + sh2s[64 + d];
    float gg = acc[i][2] + sh2s[128 + d];
    float og = acc[i][3] + sh2s[192 + d];
    float c2 = sigf(fg) * c1s[d] + sigf(ig) * tanhf(gg);
    float q2 = sigf(og) * tanhf(c2);
    qstar[(size_t)row * 128 + d] = q2;
  }
}

// ---------------- K6: attention step 2, wave-per-graph, online softmax, single pass ----------------
__global__ __launch_bounds__(256) void k_attn2(const float* __restrict__ noisy, const int* __restrict__ off,
                                               float* __restrict__ qstar) {
  int wg = blockIdx.x * 4 + (threadIdx.x >> 6);
  int lane = threadIdx.x & 63;
  int n0 = off[wg], cnt = off[wg + 1] - n0;
  float q2v = qstar[(size_t)wg * 128 + lane];
  if (cnt == 0) { qstar[(size_t)wg * 128 + 64 + lane] = 0.f; return; }
  const float* np_ = noisy + (size_t)n0 * 64 + lane;
  float mrun = -INFINITY, lrun = 0.f, racc = 0.f;
  for (int n = 0; n < cnt; n++) {
    float nv = np_[(size_t)n * 64];
    float ev = wave_sum(nv * q2v);
    float mnew = fmaxf(mrun, ev);
    float scale = expf(mrun - mnew);
    float p = expf(ev - mnew);
    lrun = fmaf(lrun, scale, p);
    racc = fmaf(racc, scale, p * nv);
    mrun = mnew;
  }
  qstar[(size_t)wg * 128 + 64 + lane] = racc / lrun;
}

// ---------------- K7/8/9: predictor linear layers ----------------
template <int KDIM, bool RELU>
__global__ __launch_bounds__(256) void k_linear(const float* __restrict__ A, const float* __restrict__ W,
                                                const float* __restrict__ bias, float* __restrict__ C, int ldc) {
  __shared__ float As[64][68];
  __shared__ float Wt[64][68];
  int tid = threadIdx.x, ty = tid >> 4, tx = tid & 15;
  int n0 = blockIdx.x * 64, c0 = blockIdx.y * 64;
  float acc[4][4] = {};
  for (int kt = 0; kt < KDIM; kt += 64) {
    __syncthreads();
    load_A64(A, KDIM, n0, kt, As, tid);
    load_Wt64(W, KDIM, c0, kt, Wt, tid);
    __syncthreads();
    mm64(As, Wt, ty, tx, acc);
  }
#pragma unroll
  for (int i = 0; i < 4; i++) {
    int row = n0 + ty * 4 + i;
    float4 o;
    float v0 = acc[i][0] + bias[c0 + tx * 4 + 0];
    float v1 = acc[i][1] + bias[c0 + tx * 4 + 1];
    float v2 = acc[i][2] + bias[c0 + tx * 4 + 2];
    float v3 = acc[i][3] + bias[c0 + tx * 4 + 3];
    if (RELU) { v0 = fmaxf(v0, 0.f); v1 = fmaxf(v1, 0.f); v2 = fmaxf(v2, 0.f); v3 = fmaxf(v3, 0.f); }
    o.x = v0; o.y = v1; o.z = v2; o.w = v3;
    *(float4*)&C[(size_t)row * ldc + c0 + tx * 4] = o;
  }
}

// ---------------- K10: final scalars ----------------
__global__ __launch_bounds__(256) void k_final(const float* __restrict__ klp, const int* __restrict__ presCnt,
                                               float* __restrict__ out) {
  __shared__ float red[256];
  float s = 0.0f;
  for (int i = threadIdx.x; i < B_GR; i += 256) s += klp[i];
  red[threadIdx.x] = s;
  __syncthreads();
  for (int st = 128; st > 0; st >>= 1) {
    if (threadIdx.x < st) red[threadIdx.x] += red[threadIdx.x + st];
    __syncthreads();
  }
  if (threadIdx.x == 0) {
    out[(size_t)B_GR * 64] = red[0] / (float)(B_GR * 64);
    out[(size_t)B_GR * 64 + 1] = (float)(*presCnt) / (float)N_TOT;
  }
}

// ---------------- launcher ----------------
extern "C" void kernel_launch(void* const* d_in, const int* in_sizes, int n_in,
                              void* d_out, int out_size, void* d_ws, size_t ws_size,
                              hipStream_t stream) {
  const float* features = (const float*)d_in[0];
  const int*   bidx     = (const int*)d_in[1];
  const float* eps_gate = (const float*)d_in[2];
  const float* noise    = (const float*)d_in[3];
  const float* c_w1 = (const float*)d_in[4];
  const float* c_b1 = (const float*)d_in[5];
  const float* bn_g = (const float*)d_in[6];
  const float* bn_b = (const float*)d_in[7];
  const float* c_w2 = (const float*)d_in[8];
  const float* c_b2 = (const float*)d_in[9];
  const float* wih  = (const float*)d_in[10];
  const float* whh  = (const float*)d_in[11];
  const float* bih  = (const float*)d_in[12];
  const float* bhh  = (const float*)d_in[13];
  const float* p_w1 = (const float*)d_in[14];
  const float* p_b1 = (const float*)d_in[15];
  const float* p_w2 = (const float*)d_in[16];
  const float* p_b2 = (const float*)d_in[17];
  const float* p_w3 = (const float*)d_in[18];
  const float* p_b3 = (const float*)d_in[19];
  float* out = (float*)d_out;

  float* wsf   = (float*)d_ws;
  int*   offp  = (int*)wsf;                                 // (B+1) ints
  float* pSum  = wsf + 16448;
  float* pSq   = pSum + 524288;
  float* aff   = pSq + 524288;                              // 128
  float* q1w   = aff + 128;
  float* c1w   = q1w + 64;
  float* sh2w  = c1w + 64;                                  // 256
  float* lamw  = sh2w + 256;                                // N
  float* noisyw = lamw + (size_t)N_TOT;                     // N*64
  float* r1w    = noisyw + (size_t)N_TOT * 64;              // B*64
  float* qstarw = r1w + (size_t)B_GR * 64;                  // B*128
  float* z1w    = qstarw + (size_t)B_GR * 128;              // B*256
  float* z2w    = z1w + (size_t)B_GR * 256;                 // B*128
  float* klpw   = z2w + (size_t)B_GR * 128;                 // B
  int*   presw  = (int*)(klpw + B_GR);

  float* lamOut = out + (size_t)B_GR * 64 + 2;

  hipMemsetAsync(presw, 0, sizeof(int), stream);

  k_offsets<<<(B_GR + 1 + 255) / 256, 256, 0, stream>>>(bidx, offp);
  k_bn_stats<<<N_TOT / 64, 256, 0, stream>>>(features, c_w1, c_b1, pSum, pSq);
  k_bn_final<<<64, 256, 0, stream>>>(pSum, pSq, bn_g, bn_b, c_b1, aff);
  k_lstm1<<<1, 256, 0, stream>>>(bih, bhh, wih, whh, q1w, c1w, sh2w);
  k_gate<<<N_TOT / 64, 256, 0, stream>>>(features, c_w1, aff, c_w2, c_b2, eps_gate, lamw, lamOut, presw);
  k_graph<<<B_GR / 4, 256, 0, stream>>>(features, noise, lamw, offp, q1w, noisyw, r1w, klpw);
  k_lstm2<<<B_GR / 16, 256, 0, stream>>>(r1w, wih, sh2w, c1w, qstarw);
  k_attn2<<<B_GR / 4, 256, 0, stream>>>(noisyw, offp, qstarw);
  k_linear<128, true><<<dim3(B_GR / 64, 4), 256, 0, stream>>>(qstarw, p_w1, p_b1, z1w, 256);
  k_linear<256, true><<<dim3(B_GR / 64, 2), 256, 0, stream>>>(z1w, p_w2, p_b2, z2w, 128);
  k_linear<128, false><<<dim3(B_GR / 64, 1), 256, 0, stream>>>(z2w, p_w3, p_b3, out, 64);
  k_final<<<1, 256, 0, stream>>>(klpw, presw, out);
}

// Round 3
// 459.959 us; speedup vs baseline: 1.4545x; 1.1422x over previous
//
#include <hip/hip_runtime.h>
#include <math.h>

#define N_TOT 524288
#define B_GR  16384

#define LOG2E 1.44269504088896f
#define LN2   0.69314718055995f

// ---------------- small device helpers ----------------
__device__ __forceinline__ float fexp2(float x) { return __builtin_amdgcn_exp2f(x); }
__device__ __forceinline__ float flog2(float x) { return __builtin_amdgcn_logf(x); }
__device__ __forceinline__ float frcp(float x)  { return __builtin_amdgcn_rcpf(x); }
__device__ __forceinline__ float sigf(float x)  { return frcp(1.0f + fexp2(-x * LOG2E)); }

__device__ __forceinline__ float wave_sum(float v) {
#pragma unroll
  for (int o = 32; o > 0; o >>= 1) v += __shfl_xor(v, o);
  return v;
}
// Reduce TWO values across 64 lanes with 8 shuffles (vs 12):
// fold offset-32 for each, pack (lo half carries p0, hi half p1), butterfly 16..1
// within halves, then one cross-swap to give every lane both sums.
__device__ __forceinline__ void wave_sum2(float p0, float p1, bool lo, float& e0, float& e1) {
  float a = p0 + __shfl_xor(p0, 32);
  float b = p1 + __shfl_xor(p1, 32);
  float c = lo ? a : b;
#pragma unroll
  for (int o = 16; o > 0; o >>= 1) c += __shfl_xor(c, o);
  float d = __shfl_xor(c, 32);
  e0 = lo ? c : d;
  e1 = lo ? d : c;
}

// ---------------- 64x64 f32 register-tiled GEMM pieces ----------------
__device__ __forceinline__ void load_A64(const float* __restrict__ A, size_t lda, int n0, int k0,
                                         float (*As)[68], int tid) {
#pragma unroll
  for (int s = 0; s < 4; s++) {
    int e4 = tid * 4 + s * 1024;
    int r = e4 >> 6, k = e4 & 63;
    *(float4*)&As[r][k] = *(const float4*)&A[(size_t)(n0 + r) * lda + k0 + k];
  }
}
__device__ __forceinline__ void load_Wt64(const float* __restrict__ W, size_t ldw, int c0, int k0,
                                          float (*Wt)[68], int tid) {
#pragma unroll
  for (int s = 0; s < 4; s++) {
    int e4 = tid * 4 + s * 1024;
    int c = e4 >> 6, k = e4 & 63;
    float4 v = *(const float4*)&W[(size_t)(c0 + c) * ldw + k0 + k];
    Wt[k + 0][c] = v.x; Wt[k + 1][c] = v.y; Wt[k + 2][c] = v.z; Wt[k + 3][c] = v.w;
  }
}
__device__ __forceinline__ void mm64(const float (*As)[68], const float (*Wt)[68],
                                     int ty, int tx, float acc[4][4]) {
#pragma unroll
  for (int k4 = 0; k4 < 64; k4 += 4) {
    float4 b0 = *(const float4*)&Wt[k4 + 0][tx * 4];
    float4 b1 = *(const float4*)&Wt[k4 + 1][tx * 4];
    float4 b2 = *(const float4*)&Wt[k4 + 2][tx * 4];
    float4 b3 = *(const float4*)&Wt[k4 + 3][tx * 4];
#pragma unroll
    for (int i = 0; i < 4; i++) {
      float4 a = *(const float4*)&As[ty * 4 + i][k4];
      acc[i][0] = fmaf(a.w, b3.x, fmaf(a.z, b2.x, fmaf(a.y, b1.x, fmaf(a.x, b0.x, acc[i][0]))));
      acc[i][1] = fmaf(a.w, b3.y, fmaf(a.z, b2.y, fmaf(a.y, b1.y, fmaf(a.x, b0.y, acc[i][1]))));
      acc[i][2] = fmaf(a.w, b3.z, fmaf(a.z, b2.z, fmaf(a.y, b1.z, fmaf(a.x, b0.z, acc[i][2]))));
      acc[i][3] = fmaf(a.w, b3.w, fmaf(a.z, b2.w, fmaf(a.y, b1.w, fmaf(a.x, b0.w, acc[i][3]))));
    }
  }
}

// ---------------- K0: graph offsets via binary search (batch_index is sorted) ----------------
__global__ void k_offsets(const int* __restrict__ idx, int* __restrict__ off) {
  int b = blockIdx.x * blockDim.x + threadIdx.x;
  if (b > B_GR) return;
  if (b == B_GR) { off[B_GR] = N_TOT; return; }
  int lo = 0, hi = N_TOT;
  while (lo < hi) { int mid = (lo + hi) >> 1; if (idx[mid] < b) lo = mid + 1; else hi = mid; }
  off[b] = lo;
}

// ---------------- K1: h = X@W1^T + b1, per-block column sum/sumsq partials ----------------
__global__ __launch_bounds__(256) void k_bn_stats(const float* __restrict__ X, const float* __restrict__ W,
                                                  const float* __restrict__ b1,
                                                  float* __restrict__ pSum, float* __restrict__ pSq) {
  __shared__ float As[64][68];
  __shared__ float Wt[64][68];
  int tid = threadIdx.x, ty = tid >> 4, tx = tid & 15;
  int n0 = blockIdx.x * 64;
  float acc[4][4] = {};
  load_A64(X, 64, n0, 0, As, tid);
  load_Wt64(W, 64, 0, 0, Wt, tid);
  __syncthreads();
  mm64(As, Wt, ty, tx, acc);
  float cs[4] = {0, 0, 0, 0}, cq[4] = {0, 0, 0, 0};
#pragma unroll
  for (int j = 0; j < 4; j++) {
    float bb = b1[tx * 4 + j];
#pragma unroll
    for (int i = 0; i < 4; i++) {
      float h = acc[i][j] + bb;
      cs[j] += h; cq[j] += h * h;
    }
  }
  __syncthreads();
  float* red = &As[0][0];
#pragma unroll
  for (int j = 0; j < 4; j++) {
    red[ty * 64 + tx * 4 + j] = cs[j];
    red[1024 + ty * 64 + tx * 4 + j] = cq[j];
  }
  __syncthreads();
  if (tid < 64) {
    float s = 0, q = 0;
#pragma unroll
    for (int t = 0; t < 16; t++) { s += red[t * 64 + tid]; q += red[1024 + t * 64 + tid]; }
    pSum[(size_t)blockIdx.x * 64 + tid] = s;
    pSq[(size_t)blockIdx.x * 64 + tid] = q;
  }
}

// ---------------- K2a: finalize BN -> affine aff[0:64]=A, aff[64:128]=C ----------------
__global__ __launch_bounds__(256) void k_bn_final(const float* __restrict__ pSum, const float* __restrict__ pSq,
                                                  const float* __restrict__ bn_g, const float* __restrict__ bn_b,
                                                  const float* __restrict__ c_b1, float* __restrict__ aff) {
  int c = blockIdx.x;
  float s = 0, q = 0;
  for (int i = threadIdx.x; i < 8192; i += 256) {
    s += pSum[(size_t)i * 64 + c];
    q += pSq[(size_t)i * 64 + c];
  }
  __shared__ float rs[256], rq[256];
  rs[threadIdx.x] = s; rq[threadIdx.x] = q;
  __syncthreads();
  for (int st = 128; st > 0; st >>= 1) {
    if (threadIdx.x < st) { rs[threadIdx.x] += rs[threadIdx.x + st]; rq[threadIdx.x] += rq[threadIdx.x + st]; }
    __syncthreads();
  }
  if (threadIdx.x == 0) {
    float mu = rs[0] / (float)N_TOT;
    float var = rq[0] / (float)N_TOT - mu * mu;
    var = fmaxf(var, 0.0f);
    float A = bn_g[c] * rsqrtf(var + 1e-5f);
    aff[c] = A;
    aff[64 + c] = bn_b[c] + (c_b1[c] - mu) * A;
  }
}

// ---------------- K2b: LSTM step1 from biases only; shared part of step-2 gates ----------------
__global__ __launch_bounds__(256) void k_lstm1(const float* __restrict__ bih, const float* __restrict__ bhh,
                                               const float* __restrict__ wih, const float* __restrict__ whh,
                                               float* __restrict__ q1, float* __restrict__ c1, float* __restrict__ sh2) {
  __shared__ float g1[256];
  __shared__ float q1s[64];
  int tid = threadIdx.x;
  g1[tid] = bih[tid] + bhh[tid];
  __syncthreads();
  if (tid < 64) {
    float ig = sigf(g1[tid]);
    float gg = tanhf(g1[128 + tid]);
    float cc = ig * gg;
    float og = sigf(g1[192 + tid]);
    float qv = og * tanhf(cc);
    q1s[tid] = qv; q1[tid] = qv; c1[tid] = cc;
  }
  __syncthreads();
  float acc = g1[tid];
  for (int k = 0; k < 64; k++)
    acc = fmaf(wih[(size_t)tid * 128 + k] + whh[(size_t)tid * 64 + k], q1s[k], acc);
  sh2[tid] = acc;
}

// ---------------- K3: recompute h, BN-affine+ReLU, p, lambda; preserve count ----------------
__global__ __launch_bounds__(256) void k_gate(const float* __restrict__ X, const float* __restrict__ W,
                                              const float* __restrict__ aff, const float* __restrict__ w2,
                                              const float* __restrict__ cb2, const float* __restrict__ eps_gate,
                                              float* __restrict__ lamWS, float* __restrict__ lamOut,
                                              int* __restrict__ presCnt) {
  __shared__ float As[64][68];
  __shared__ float Wt[64][68];
  __shared__ float predR[64][17];
  __shared__ float A2s[64], C2s[64], w2s[64];
  int tid = threadIdx.x, ty = tid >> 4, tx = tid & 15;
  int n0 = blockIdx.x * 64;
  if (tid < 64) { A2s[tid] = aff[tid]; C2s[tid] = aff[64 + tid]; w2s[tid] = w2[tid]; }
  float acc[4][4] = {};
  load_A64(X, 64, n0, 0, As, tid);
  load_Wt64(W, 64, 0, 0, Wt, tid);
  __syncthreads();
  mm64(As, Wt, ty, tx, acc);
  float pp[4] = {0, 0, 0, 0};
#pragma unroll
  for (int j = 0; j < 4; j++) {
    int c = tx * 4 + j;
    float A2 = A2s[c], C2 = C2s[c], wv = w2s[c];
#pragma unroll
    for (int i = 0; i < 4; i++) {
      float v = fmaxf(fmaf(acc[i][j], A2, C2), 0.0f);
      pp[i] = fmaf(v, wv, pp[i]);
    }
  }
#pragma unroll
  for (int i = 0; i < 4; i++) predR[ty * 4 + i][tx] = pp[i];
  __syncthreads();
  if (tid < 64) {
    float p = cb2[0];
#pragma unroll
    for (int t = 0; t < 16; t++) p += predR[tid][t];
    float eg = eps_gate[n0 + tid];
    float eps = 0.9999f - 0.9998f * eg;
    float gi = (flog2(eps) - flog2(1.0f - eps)) * LN2;
    float lam = sigf(gi + p);
    lamWS[n0 + tid] = lam;
    lamOut[n0 + tid] = lam;
    unsigned long long m = __ballot(p > 0.0f);
    if (tid == 0) atomicAdd(presCnt, (int)__popcll(m));
  }
}

// ---------------- K4: wave-per-graph: stats, noisy, KL, 2-stream deferred-max online softmax ----------------
__global__ __launch_bounds__(256) void k_graph(const float* __restrict__ X, const float* __restrict__ noise,
                                               const float* __restrict__ lam, const int* __restrict__ off,
                                               const float* __restrict__ q1g,
                                               float* __restrict__ noisy, float* __restrict__ r1,
                                               float* __restrict__ klp) {
  int wg = blockIdx.x * 4 + (threadIdx.x >> 6);
  int lane = threadIdx.x & 63;
  bool lo = lane < 32;
  int n0 = off[wg], cnt = off[wg + 1] - n0;
  if (cnt == 0) {
    r1[(size_t)wg * 64 + lane] = 0.0f;
    if (lane == 0) klp[wg] = 0.0f;
    return;
  }
  float q1v2 = q1g[lane] * LOG2E;   // fold log2(e) into q so logits live in exp2 domain
  const float* xp = X + (size_t)n0 * 64 + lane;
  // pass 1: per-dim mean / unbiased std (lane-local, 2 accumulator streams for ILP)
  float s0 = 0.f, q0 = 0.f, s1 = 0.f, q1_ = 0.f;
  int n = 0;
  for (; n + 2 <= cnt; n += 2) {
    float a = xp[(size_t)n * 64], b = xp[(size_t)(n + 1) * 64];
    s0 += a; q0 = fmaf(a, a, q0);
    s1 += b; q1_ = fmaf(b, b, q1_);
  }
  if (n < cnt) { float a = xp[(size_t)n * 64]; s0 += a; q0 = fmaf(a, a, q0); }
  float c = (float)cnt;
  float mean = (s0 + s1) / c;
  float var = fmaxf(((q0 + q1_) - c * mean * mean) / fmaxf(c - 1.f, 1.f), 0.f);
  float sd = sqrtf(var);
  float inv = frcp(sd + 1e-7f);
  float S1 = wave_sum(sd * sd * inv * inv);
  // pass 2: noisy + KL partials + 2-stream online softmax (defer-max, THR=8)
  const float* zp = noise + (size_t)n0 * 64 + lane;
  float* nw = noisy + (size_t)n0 * 64 + lane;
  const float THR = 8.f;
  float t2acc = 0.f, sumOm2 = 0.f;
  float m0 = -INFINITY, l0 = 0.f, r0 = 0.f;
  float m1 = -INFINITY, l1 = 0.f, r1a = 0.f;
  n = 0;
  for (; n + 2 <= cnt; n += 2) {
    float lamA = lam[n0 + n], lamB = lam[n0 + n + 1];
    float xA = xp[(size_t)n * 64], xB = xp[(size_t)(n + 1) * 64];
    float zA = zp[(size_t)n * 64], zB = zp[(size_t)(n + 1) * 64];
    float omA = 1.f - lamA, omB = 1.f - lamB;
    float nvA = fmaf(lamA, xA, omA * mean) + zA * (omA * sd);
    float nvB = fmaf(lamB, xB, omB * mean) + zB * (omB * sd);
    nw[(size_t)n * 64] = nvA;
    nw[(size_t)(n + 1) * 64] = nvB;
    float ldA = lamA * (xA - mean) * inv; t2acc = fmaf(ldA, ldA, t2acc);
    float ldB = lamB * (xB - mean) * inv; t2acc = fmaf(ldB, ldB, t2acc);
    sumOm2 = fmaf(omA, omA, sumOm2); sumOm2 = fmaf(omB, omB, sumOm2);
    float e0, e1;
    wave_sum2(nvA * q1v2, nvB * q1v2, lo, e0, e1);
    if (e0 > m0 + THR) { float sc = fexp2(m0 - e0); l0 *= sc; r0 *= sc; m0 = e0; }
    float pA = fexp2(e0 - m0); l0 += pA; r0 = fmaf(pA, nvA, r0);
    if (e1 > m1 + THR) { float sc = fexp2(m1 - e1); l1 *= sc; r1a *= sc; m1 = e1; }
    float pB = fexp2(e1 - m1); l1 += pB; r1a = fmaf(pB, nvB, r1a);
  }
  if (n < cnt) {
    float lamA = lam[n0 + n];
    float xA = xp[(size_t)n * 64];
    float zA = zp[(size_t)n * 64];
    float omA = 1.f - lamA;
    float nvA = fmaf(lamA, xA, omA * mean) + zA * (omA * sd);
    nw[(size_t)n * 64] = nvA;
    float ldA = lamA * (xA - mean) * inv; t2acc = fmaf(ldA, ldA, t2acc);
    sumOm2 = fmaf(omA, omA, sumOm2);
    float e0 = wave_sum(nvA * q1v2);
    if (e0 > m0 + THR) { float sc = fexp2(m0 - e0); l0 *= sc; r0 *= sc; m0 = e0; }
    float pA = fexp2(e0 - m0); l0 += pA; r0 = fmaf(pA, nvA, r0);
  }
  // merge the two streams
  float M = fmaxf(m0, m1);
  float sc0 = fexp2(m0 - M), sc1 = fexp2(m1 - M);
  float L = l0 * sc0 + l1 * sc1;
  float R = r0 * sc0 + r1a * sc1;
  r1[(size_t)wg * 64 + lane] = R / L;
  float t2tot = wave_sum(t2acc);
  if (lane == 0) klp[wg] = fmaf(0.5f * sumOm2, S1, t2tot);
}

// ---------------- K5: Set2Set step-2 LSTM: gates = sh2 + r1 @ R^T, 16 graphs/block ----------------
__global__ __launch_bounds__(256) void k_lstm2(const float* __restrict__ r1, const float* __restrict__ wih,
                                               const float* __restrict__ sh2, const float* __restrict__ c1g,
                                               float* __restrict__ qstar) {
  __shared__ float Rs[2][64][64];
  __shared__ float r1s[16][64];
  __shared__ float sh2s[256], c1s[64];
  int tid = threadIdx.x;
  int d = tid & 63, rg = tid >> 6;
  int g0 = blockIdx.x * 16;
  sh2s[tid] = sh2[tid];
  if (tid < 64) c1s[tid] = c1g[tid];
  {
    int e4 = tid * 4;
    int r = e4 >> 6, k = e4 & 63;
    *(float4*)&r1s[r][k] = *(const float4*)&r1[(size_t)(g0 + r) * 64 + k];
  }
  float acc[4][4] = {};
#pragma unroll
  for (int jp = 0; jp < 2; jp++) {
    __syncthreads();
    {
      int gate = jp * 2 + (tid >= 128 ? 1 : 0);
      int dd2 = tid & 63;
      if ((tid & 127) < 64) {
        int row = gate * 64 + dd2;
        const float* src = &wih[(size_t)row * 128 + 64];
        for (int k = 0; k < 64; k += 4) {
          float4 v = *(const float4*)&src[k];
          Rs[gate - jp * 2][k + 0][dd2] = v.x;
          Rs[gate - jp * 2][k + 1][dd2] = v.y;
          Rs[gate - jp * 2][k + 2][dd2] = v.z;
          Rs[gate - jp * 2][k + 3][dd2] = v.w;
        }
      }
    }
    __syncthreads();
    for (int k = 0; k < 64; k++) {
      float bj0 = Rs[0][k][d];
      float bj1 = Rs[1][k][d];
#pragma unroll
      for (int i = 0; i < 4; i++) {
        float a = r1s[rg * 4 + i][k];
        acc[i][jp * 2 + 0] = fmaf(a, bj0, acc[i][jp * 2 + 0]);
        acc[i][jp * 2 + 1] = fmaf(a, bj1, acc[i][jp * 2 + 1]);
      }
    }
  }
#pragma unroll
  for (int i = 0; i < 4; i++) {
    int row = g0 + rg * 4 + i;
    float ig = acc[i][0] + sh2s[d];
    float fg = acc[i][1] + sh2s[64 + d];
    float gg = acc[i][2] + sh2s[128 + d];
    float og = acc[i][3] + sh2s[192 + d];
    float c2 = sigf(fg) * c1s[d] + sigf(ig) * tanhf(gg);
    float q2 = sigf(og) * tanhf(c2);
    qstar[(size_t)row * 128 + d] = q2;
  }
}

// ---------------- K6: attention step 2, wave-per-graph, 2-stream deferred-max online softmax ----------------
__global__ __launch_bounds__(256) void k_attn2(const float* __restrict__ noisy, const int* __restrict__ off,
                                               float* __restrict__ qstar) {
  int wg = blockIdx.x * 4 + (threadIdx.x >> 6);
  int lane = threadIdx.x & 63;
  bool lo = lane < 32;
  int n0 = off[wg], cnt = off[wg + 1] - n0;
  float q2v2 = qstar[(size_t)wg * 128 + lane] * LOG2E;
  if (cnt == 0) { qstar[(size_t)wg * 128 + 64 + lane] = 0.f; return; }
  const float* np_ = noisy + (size_t)n0 * 64 + lane;
  const float THR = 8.f;
  float m0 = -INFINITY, l0 = 0.f, r0 = 0.f;
  float m1 = -INFINITY, l1 = 0.f, r1a = 0.f;
  int n = 0;
  for (; n + 2 <= cnt; n += 2) {
    float nvA = np_[(size_t)n * 64];
    float nvB = np_[(size_t)(n + 1) * 64];
    float e0, e1;
    wave_sum2(nvA * q2v2, nvB * q2v2, lo, e0, e1);
    if (e0 > m0 + THR) { float sc = fexp2(m0 - e0); l0 *= sc; r0 *= sc; m0 = e0; }
    float pA = fexp2(e0 - m0); l0 += pA; r0 = fmaf(pA, nvA, r0);
    if (e1 > m1 + THR) { float sc = fexp2(m1 - e1); l1 *= sc; r1a *= sc; m1 = e1; }
    float pB = fexp2(e1 - m1); l1 += pB; r1a = fmaf(pB, nvB, r1a);
  }
  if (n < cnt) {
    float nvA = np_[(size_t)n * 64];
    float e0 = wave_sum(nvA * q2v2);
    if (e0 > m0 + THR) { float sc = fexp2(m0 - e0); l0 *= sc; r0 *= sc; m0 = e0; }
    float pA = fexp2(e0 - m0); l0 += pA; r0 = fmaf(pA, nvA, r0);
  }
  float M = fmaxf(m0, m1);
  float sc0 = fexp2(m0 - M), sc1 = fexp2(m1 - M);
  float L = l0 * sc0 + l1 * sc1;
  float R = r0 * sc0 + r1a * sc1;
  qstar[(size_t)wg * 128 + 64 + lane] = R / L;
}

// ---------------- K7/8/9: predictor linear layers ----------------
template <int KDIM, bool RELU>
__global__ __launch_bounds__(256) void k_linear(const float* __restrict__ A, const float* __restrict__ W,
                                                const float* __restrict__ bias, float* __restrict__ C, int ldc) {
  __shared__ float As[64][68];
  __shared__ float Wt[64][68];
  int tid = threadIdx.x, ty = tid >> 4, tx = tid & 15;
  int n0 = blockIdx.x * 64, c0 = blockIdx.y * 64;
  float acc[4][4] = {};
  for (int kt = 0; kt < KDIM; kt += 64) {
    __syncthreads();
    load_A64(A, KDIM, n0, kt, As, tid);
    load_Wt64(W, KDIM, c0, kt, Wt, tid);
    __syncthreads();
    mm64(As, Wt, ty, tx, acc);
  }
#pragma unroll
  for (int i = 0; i < 4; i++) {
    int row = n0 + ty * 4 + i;
    float4 o;
    float v0 = acc[i][0] + bias[c0 + tx * 4 + 0];
    float v1 = acc[i][1] + bias[c0 + tx * 4 + 1];
    float v2 = acc[i][2] + bias[c0 + tx * 4 + 2];
    float v3 = acc[i][3] + bias[c0 + tx * 4 + 3];
    if (RELU) { v0 = fmaxf(v0, 0.f); v1 = fmaxf(v1, 0.f); v2 = fmaxf(v2, 0.f); v3 = fmaxf(v3, 0.f); }
    o.x = v0; o.y = v1; o.z = v2; o.w = v3;
    *(float4*)&C[(size_t)row * ldc + c0 + tx * 4] = o;
  }
}

// ---------------- K10: final scalars ----------------
__global__ __launch_bounds__(256) void k_final(const float* __restrict__ klp, const int* __restrict__ presCnt,
                                               float* __restrict__ out) {
  __shared__ float red[256];
  float s = 0.0f;
  for (int i = threadIdx.x; i < B_GR; i += 256) s += klp[i];
  red[threadIdx.x] = s;
  __syncthreads();
  for (int st = 128; st > 0; st >>= 1) {
    if (threadIdx.x < st) red[threadIdx.x] += red[threadIdx.x + st];
    __syncthreads();
  }
  if (threadIdx.x == 0) {
    out[(size_t)B_GR * 64] = red[0] / (float)(B_GR * 64);
    out[(size_t)B_GR * 64 + 1] = (float)(*presCnt) / (float)N_TOT;
  }
}

// ---------------- launcher ----------------
extern "C" void kernel_launch(void* const* d_in, const int* in_sizes, int n_in,
                              void* d_out, int out_size, void* d_ws, size_t ws_size,
                              hipStream_t stream) {
  const float* features = (const float*)d_in[0];
  const int*   bidx     = (const int*)d_in[1];
  const float* eps_gate = (const float*)d_in[2];
  const float* noise    = (const float*)d_in[3];
  const float* c_w1 = (const float*)d_in[4];
  const float* c_b1 = (const float*)d_in[5];
  const float* bn_g = (const float*)d_in[6];
  const float* bn_b = (const float*)d_in[7];
  const float* c_w2 = (const float*)d_in[8];
  const float* c_b2 = (const float*)d_in[9];
  const float* wih  = (const float*)d_in[10];
  const float* whh  = (const float*)d_in[11];
  const float* bih  = (const float*)d_in[12];
  const float* bhh  = (const float*)d_in[13];
  const float* p_w1 = (const float*)d_in[14];
  const float* p_b1 = (const float*)d_in[15];
  const float* p_w2 = (const float*)d_in[16];
  const float* p_b2 = (const float*)d_in[17];
  const float* p_w3 = (const float*)d_in[18];
  const float* p_b3 = (const float*)d_in[19];
  float* out = (float*)d_out;

  float* wsf   = (float*)d_ws;
  int*   offp  = (int*)wsf;                                 // (B+1) ints
  float* pSum  = wsf + 16448;
  float* pSq   = pSum + 524288;
  float* aff   = pSq + 524288;                              // 128
  float* q1w   = aff + 128;
  float* c1w   = q1w + 64;
  float* sh2w  = c1w + 64;                                  // 256
  float* lamw  = sh2w + 256;                                // N
  float* noisyw = lamw + (size_t)N_TOT;                     // N*64
  float* r1w    = noisyw + (size_t)N_TOT * 64;              // B*64
  float* qstarw = r1w + (size_t)B_GR * 64;                  // B*128
  float* z1w    = qstarw + (size_t)B_GR * 128;              // B*256
  float* z2w    = z1w + (size_t)B_GR * 256;                 // B*128
  float* klpw   = z2w + (size_t)B_GR * 128;                 // B
  int*   presw  = (int*)(klpw + B_GR);

  float* lamOut = out + (size_t)B_GR * 64 + 2;

  hipMemsetAsync(presw, 0, sizeof(int), stream);

  k_offsets<<<(B_GR + 1 + 255) / 256, 256, 0, stream>>>(bidx, offp);
  k_bn_stats<<<N_TOT / 64, 256, 0, stream>>>(features, c_w1, c_b1, pSum, pSq);
  k_bn_final<<<64, 256, 0, stream>>>(pSum, pSq, bn_g, bn_b, c_b1, aff);
  k_lstm1<<<1, 256, 0, stream>>>(bih, bhh, wih, whh, q1w, c1w, sh2w);
  k_gate<<<N_TOT / 64, 256, 0, stream>>>(features, c_w1, aff, c_w2, c_b2, eps_gate, lamw, lamOut, presw);
  k_graph<<<B_GR / 4, 256, 0, stream>>>(features, noise, lamw, offp, q1w, noisyw, r1w, klpw);
  k_lstm2<<<B_GR / 16, 256, 0, stream>>>(r1w, wih, sh2w, c1w, qstarw);
  k_attn2<<<B_GR / 4, 256, 0, stream>>>(noisyw, offp, qstarw);
  k_linear<128, true><<<dim3(B_GR / 64, 4), 256, 0, stream>>>(qstarw, p_w1, p_b1, z1w, 256);
  k_linear<256, true><<<dim3(B_GR / 64, 2), 256, 0, stream>>>(z1w, p_w2, p_b2, z2w, 128);
  k_linear<128, false><<<dim3(B_GR / 64, 1), 256, 0, stream>>>(z2w, p_w3, p_b3, out, 64);
  k_final<<<1, 256, 0, stream>>>(klpw, presw, out);
}